// Round 1
// baseline (618.518 us; speedup 1.0000x reference)
//
#include <hip/hip_runtime.h>

#define NN 8192
#define THREADS 256
#define BLOCKS 2048
#define NVEC (NN * NN / 4)           // 16,777,216 float4 elements
#define GSTRIDE (BLOCKS * THREADS)   // 524,288 float4 per grid sweep
#define ITERS (NVEC / GSTRIDE)       // 32 iterations per thread, exact
#define UNROLL 4

static_assert(NVEC % GSTRIDE == 0, "exact grid-stride trip count");
static_assert(ITERS % UNROLL == 0, "exact unroll");

typedef float f4 __attribute__((ext_vector_type(4)));

__global__ __launch_bounds__(THREADS) void fused_update_reduce(
    const float* __restrict__ a,      // [N] neural_activities
    const float* __restrict__ W,      // [N,N] connection_matrix
    const float* __restrict__ Cin,    // [N,N] correlation_matrix
    float* __restrict__ Cout,         // [N,N] output C
    double* __restrict__ partials)    // [BLOCKS*3]
{
    const float decay = 0.9f;
    const float om    = 0.1f;   // jnp.float32(1.0 - 0.9) == 0.1f

    const f4* __restrict__ C4 = (const f4*)Cin;
    const f4* __restrict__ W4 = (const f4*)W;
    f4* __restrict__ O4       = (f4*)Cout;

    const unsigned t0 = blockIdx.x * (unsigned)THREADS + threadIdx.x;

    double s_abs = 0.0, s_w = 0.0, s_cw = 0.0;

    for (int o = 0; o < ITERS / UNROLL; ++o) {
        // ---- batch the streaming loads: 8 float4 loads in flight ----
        unsigned v[UNROLL];
        f4 c[UNROLL], w[UNROLL];
        #pragma unroll
        for (int u = 0; u < UNROLL; ++u) {
            v[u] = t0 + (unsigned)(o * UNROLL + u) * (unsigned)GSTRIDE;
            c[u] = C4[v[u]];
            w[u] = W4[v[u]];
        }

        float f_abs = 0.f, f_w = 0.f, f_cw = 0.f;
        #pragma unroll
        for (int u = 0; u < UNROLL; ++u) {
            const unsigned base = v[u] << 2;          // float index
            const int row  = (int)(base >> 13);       // N = 8192 = 2^13
            const int col0 = (int)(base & (NN - 1));  // multiple of 4

            const f4   a4 = *(const f4*)(a + col0);   // L1/L2-resident
            const float ar = a[row];

            float o0 = decay * c[u].x + om * ar * a4.x;
            float o1 = decay * c[u].y + om * ar * a4.y;
            float o2 = decay * c[u].z + om * ar * a4.z;
            float o3 = decay * c[u].w + om * ar * a4.w;

            // diagonal untouched
            if (row == col0)     o0 = c[u].x;
            if (row == col0 + 1) o1 = c[u].y;
            if (row == col0 + 2) o2 = c[u].z;
            if (row == col0 + 3) o3 = c[u].w;

            f4 out4 = { o0, o1, o2, o3 };
            // nt store: Cout is write-once — keep it out of L2/L3 so the
            // read streams retain their Infinity-Cache residency
            __builtin_nontemporal_store(out4, &O4[v[u]]);

            const float ab0 = fabsf(o0), ab1 = fabsf(o1),
                        ab2 = fabsf(o2), ab3 = fabsf(o3);

            f_abs += (ab0 + ab1) + (ab2 + ab3);
            f_w   += (w[u].x + w[u].y) + (w[u].z + w[u].w);
            f_cw  += (ab0 * w[u].x + ab1 * w[u].y) + (ab2 * w[u].z + ab3 * w[u].w);
        }
        // fold into double once per batch (short FP64 dependency chain)
        s_abs += (double)f_abs;
        s_w   += (double)f_w;
        s_cw  += (double)f_cw;
    }

    // wave-level reduction (64 lanes)
    for (int off = 32; off > 0; off >>= 1) {
        s_abs += __shfl_down(s_abs, off, 64);
        s_w   += __shfl_down(s_w,   off, 64);
        s_cw  += __shfl_down(s_cw,  off, 64);
    }

    __shared__ double sh[3][THREADS / 64];
    const int lane = threadIdx.x & 63;
    const int wv   = threadIdx.x >> 6;
    if (lane == 0) {
        sh[0][wv] = s_abs; sh[1][wv] = s_w; sh[2][wv] = s_cw;
    }
    __syncthreads();
    if (threadIdx.x == 0) {
        double t0d = 0.0, t1d = 0.0, t2d = 0.0;
        #pragma unroll
        for (int i = 0; i < THREADS / 64; ++i) {
            t0d += sh[0][i]; t1d += sh[1][i]; t2d += sh[2][i];
        }
        partials[blockIdx.x * 3 + 0] = t0d;
        partials[blockIdx.x * 3 + 1] = t1d;
        partials[blockIdx.x * 3 + 2] = t2d;
    }
}

__global__ __launch_bounds__(256) void finalize_scalars(
    const double* __restrict__ partials,   // [BLOCKS*3]
    const float* __restrict__ coh_in,      // [1]
    const float* __restrict__ integ_in,    // [1]
    float* __restrict__ out_scalars)       // [3]: coherence, integration, synchrony
{
    double s_abs = 0.0, s_w = 0.0, s_cw = 0.0;
    for (int i = threadIdx.x; i < BLOCKS; i += blockDim.x) {
        s_abs += partials[i * 3 + 0];
        s_w   += partials[i * 3 + 1];
        s_cw  += partials[i * 3 + 2];
    }
    for (int off = 32; off > 0; off >>= 1) {
        s_abs += __shfl_down(s_abs, off, 64);
        s_w   += __shfl_down(s_w,   off, 64);
        s_cw  += __shfl_down(s_cw,  off, 64);
    }
    __shared__ double sh[3][4];
    const int lane = threadIdx.x & 63;
    const int wv   = threadIdx.x >> 6;
    if (lane == 0) { sh[0][wv] = s_abs; sh[1][wv] = s_w; sh[2][wv] = s_cw; }
    __syncthreads();
    if (threadIdx.x == 0) {
        double t_abs = 0.0, t_w = 0.0, t_cw = 0.0;
        #pragma unroll
        for (int i = 0; i < 4; ++i) { t_abs += sh[0][i]; t_w += sh[1][i]; t_cw += sh[2][i]; }

        const float decay = 0.9f, om = 0.1f;
        const double n_conn = (double)NN * (double)(NN - 1);
        const double n_tot  = (double)NN * (double)NN;

        const float coherence = decay * coh_in[0] + om * (float)(t_abs / n_conn);
        float integration = integ_in[0];
        if (t_w > 0.0) {
            integration = decay * integ_in[0] + om * (float)(t_cw / t_w);
        }
        const float synchrony = (float)(t_abs / n_tot);

        out_scalars[0] = coherence;
        out_scalars[1] = integration;
        out_scalars[2] = synchrony;
    }
}

extern "C" void kernel_launch(void* const* d_in, const int* in_sizes, int n_in,
                              void* d_out, int out_size, void* d_ws, size_t ws_size,
                              hipStream_t stream) {
    const float* a     = (const float*)d_in[0];   // neural_activities [N]
    const float* W     = (const float*)d_in[1];   // connection_matrix [N,N]
    const float* Cin   = (const float*)d_in[2];   // correlation_matrix [N,N]
    const float* coh   = (const float*)d_in[3];   // coherence_strength [1]
    const float* integ = (const float*)d_in[4];   // integration_measure [1]

    float*  Cout     = (float*)d_out;                       // [N,N]
    float*  scalars  = (float*)d_out + (long long)NN * NN;  // [3]
    double* partials = (double*)d_ws;                       // [BLOCKS*3]

    fused_update_reduce<<<BLOCKS, THREADS, 0, stream>>>(a, W, Cin, Cout, partials);
    finalize_scalars<<<1, 256, 0, stream>>>(partials, coh, integ, scalars);
}

// Round 4
// 608.449 us; speedup vs baseline: 1.0165x; 1.0165x over previous
//
#include <hip/hip_runtime.h>

#define NN 8192
#define THREADS 256
#define BLOCKS 2048
#define NVEC (NN * NN / 4)                    // 16,777,216 float4 elements
#define F4PB (NVEC / BLOCKS)                  // 8192 float4 per block (= 4 matrix rows)
#define UNROLL 4
#define PHASES (F4PB / (UNROLL * THREADS))    // 8 phases per block

static_assert(NVEC % BLOCKS == 0, "exact block partition");
static_assert(F4PB % (UNROLL * THREADS) == 0, "exact phase count");

typedef float f4 __attribute__((ext_vector_type(4)));

__global__ __launch_bounds__(THREADS) void fused_update_reduce(
    const float* __restrict__ a,      // [N] neural_activities
    const float* __restrict__ W,      // [N,N] connection_matrix
    const float* __restrict__ Cin,    // [N,N] correlation_matrix
    float* __restrict__ Cout,         // [N,N] output C
    double* __restrict__ partials)    // [BLOCKS*3]
{
    const float decay = 0.9f;
    const float om    = 0.1f;   // jnp.float32(1.0 - 0.9) == 0.1f

    const f4* __restrict__ C4 = (const f4*)Cin;
    const f4* __restrict__ W4 = (const f4*)W;
    f4* __restrict__ O4       = (f4*)Cout;

    // Block-contiguous partition: block b owns float4 range
    // [b*F4PB, (b+1)*F4PB) == 4 consecutive matrix rows.
    const unsigned blockbase = blockIdx.x * (unsigned)F4PB;

    double s_abs = 0.0, s_w = 0.0, s_cw = 0.0;

    for (int p = 0; p < PHASES; ++p) {
        const unsigned v0 = blockbase + (unsigned)p * (UNROLL * THREADS) + threadIdx.x;

        // ---- contiguous 16 KB read burst per stream: 4 back-to-back
        //      wave-coalesced 4 KB loads of C, then 4 of W ----
        f4 c[UNROLL], w[UNROLL];
        #pragma unroll
        for (int u = 0; u < UNROLL; ++u) c[u] = C4[v0 + u * THREADS];
        #pragma unroll
        for (int u = 0; u < UNROLL; ++u) w[u] = W4[v0 + u * THREADS];

        float f_abs = 0.f, f_w = 0.f, f_cw = 0.f;
        #pragma unroll
        for (int u = 0; u < UNROLL; ++u) {
            const unsigned v    = v0 + u * THREADS;
            const unsigned base = v << 2;             // float index
            const int row  = (int)(base >> 13);       // N = 8192 = 2^13
            const int col0 = (int)(base & (NN - 1));  // multiple of 4

            const f4    a4 = *(const f4*)(a + col0);  // L1-resident (32 KB vector)
            const float ar = a[row];                  // wave-uniform, L1 hit

            float o0 = decay * c[u].x + om * ar * a4.x;
            float o1 = decay * c[u].y + om * ar * a4.y;
            float o2 = decay * c[u].z + om * ar * a4.z;
            float o3 = decay * c[u].w + om * ar * a4.w;

            // diagonal untouched
            if (row == col0)     o0 = c[u].x;
            if (row == col0 + 1) o1 = c[u].y;
            if (row == col0 + 2) o2 = c[u].z;
            if (row == col0 + 3) o3 = c[u].w;

            f4 out4 = { o0, o1, o2, o3 };
            O4[v] = out4;   // default store: let L2/L3 write-buffer (nt regressed)

            const float ab0 = fabsf(o0), ab1 = fabsf(o1),
                        ab2 = fabsf(o2), ab3 = fabsf(o3);

            f_abs += (ab0 + ab1) + (ab2 + ab3);
            f_w   += (w[u].x + w[u].y) + (w[u].z + w[u].w);
            f_cw  += (ab0 * w[u].x + ab1 * w[u].y) + (ab2 * w[u].z + ab3 * w[u].w);
        }
        // fold into double once per phase (short FP64 dependency chain)
        s_abs += (double)f_abs;
        s_w   += (double)f_w;
        s_cw  += (double)f_cw;
    }

    // wave-level reduction (64 lanes)
    for (int off = 32; off > 0; off >>= 1) {
        s_abs += __shfl_down(s_abs, off, 64);
        s_w   += __shfl_down(s_w,   off, 64);
        s_cw  += __shfl_down(s_cw,  off, 64);
    }

    __shared__ double sh[3][THREADS / 64];
    const int lane = threadIdx.x & 63;
    const int wv   = threadIdx.x >> 6;
    if (lane == 0) {
        sh[0][wv] = s_abs; sh[1][wv] = s_w; sh[2][wv] = s_cw;
    }
    __syncthreads();
    if (threadIdx.x == 0) {
        double t0d = 0.0, t1d = 0.0, t2d = 0.0;
        #pragma unroll
        for (int i = 0; i < THREADS / 64; ++i) {
            t0d += sh[0][i]; t1d += sh[1][i]; t2d += sh[2][i];
        }
        partials[blockIdx.x * 3 + 0] = t0d;
        partials[blockIdx.x * 3 + 1] = t1d;
        partials[blockIdx.x * 3 + 2] = t2d;
    }
}

__global__ __launch_bounds__(256) void finalize_scalars(
    const double* __restrict__ partials,   // [BLOCKS*3]
    const float* __restrict__ coh_in,      // [1]
    const float* __restrict__ integ_in,    // [1]
    float* __restrict__ out_scalars)       // [3]: coherence, integration, synchrony
{
    double s_abs = 0.0, s_w = 0.0, s_cw = 0.0;
    for (int i = threadIdx.x; i < BLOCKS; i += blockDim.x) {
        s_abs += partials[i * 3 + 0];
        s_w   += partials[i * 3 + 1];
        s_cw  += partials[i * 3 + 2];
    }
    for (int off = 32; off > 0; off >>= 1) {
        s_abs += __shfl_down(s_abs, off, 64);
        s_w   += __shfl_down(s_w,   off, 64);
        s_cw  += __shfl_down(s_cw,  off, 64);
    }
    __shared__ double sh[3][4];
    const int lane = threadIdx.x & 63;
    const int wv   = threadIdx.x >> 6;
    if (lane == 0) { sh[0][wv] = s_abs; sh[1][wv] = s_w; sh[2][wv] = s_cw; }
    __syncthreads();
    if (threadIdx.x == 0) {
        double t_abs = 0.0, t_w = 0.0, t_cw = 0.0;
        #pragma unroll
        for (int i = 0; i < 4; ++i) { t_abs += sh[0][i]; t_w += sh[1][i]; t_cw += sh[2][i]; }

        const float decay = 0.9f, om = 0.1f;
        const double n_conn = (double)NN * (double)(NN - 1);
        const double n_tot  = (double)NN * (double)NN;

        const float coherence = decay * coh_in[0] + om * (float)(t_abs / n_conn);
        float integration = integ_in[0];
        if (t_w > 0.0) {
            integration = decay * integ_in[0] + om * (float)(t_cw / t_w);
        }
        const float synchrony = (float)(t_abs / n_tot);

        out_scalars[0] = coherence;
        out_scalars[1] = integration;
        out_scalars[2] = synchrony;
    }
}

extern "C" void kernel_launch(void* const* d_in, const int* in_sizes, int n_in,
                              void* d_out, int out_size, void* d_ws, size_t ws_size,
                              hipStream_t stream) {
    const float* a     = (const float*)d_in[0];   // neural_activities [N]
    const float* W     = (const float*)d_in[1];   // connection_matrix [N,N]
    const float* Cin   = (const float*)d_in[2];   // correlation_matrix [N,N]
    const float* coh   = (const float*)d_in[3];   // coherence_strength [1]
    const float* integ = (const float*)d_in[4];   // integration_measure [1]

    float*  Cout     = (float*)d_out;                       // [N,N]
    float*  scalars  = (float*)d_out + (long long)NN * NN;  // [3]
    double* partials = (double*)d_ws;                       // [BLOCKS*3]

    fused_update_reduce<<<BLOCKS, THREADS, 0, stream>>>(a, W, Cin, Cout, partials);
    finalize_scalars<<<1, 256, 0, stream>>>(partials, coh, integ, scalars);
}